// Round 1
// baseline (609.645 us; speedup 1.0000x reference)
//
#include <hip/hip_runtime.h>
#include <stdint.h>

typedef unsigned short u16;
typedef __attribute__((ext_vector_type(8))) short bf16x8;
typedef __attribute__((ext_vector_type(4))) float f32x4;

#define PTOT 36864
#define WIMG 192

__device__ __forceinline__ float bf2f(u16 h) {
    union { uint32_t u; float f; } v; v.u = ((uint32_t)h) << 16; return v.f;
}
__device__ __forceinline__ u16 f2bf(float f) {
    union { float f; uint32_t u; } v; v.f = f;
    uint32_t u = v.u;
    return (u16)((u + 0x7FFFu + ((u >> 16) & 1u)) >> 16);
}

#define ASYNC_COPY16(gp, lp)                                                     \
    __builtin_amdgcn_global_load_lds(                                            \
        (const __attribute__((address_space(1))) void*)(gp),                     \
        (__attribute__((address_space(3))) void*)(lp), 16, 0, 0)

// ---------- transpose+convert: x (b,256,P) f32 -> xt (b,P,256) bf16 ----------
__global__ __launch_bounds__(256) void k_transpose(const float* __restrict__ x,
                                                   u16* __restrict__ xt) {
    __shared__ u16 tile[32][33];
    const int tx = threadIdx.x, ty = threadIdx.y;  // (32, 8)
    const int p0 = blockIdx.x * 32, c0 = blockIdx.y * 32, b = blockIdx.z;
    const float* src = x + (size_t)b * 256 * PTOT;
    u16* dst = xt + (size_t)b * PTOT * 256;
#pragma unroll
    for (int k = 0; k < 4; ++k) {
        int c = c0 + ty + k * 8;
        tile[ty + k * 8][tx] = f2bf(src[(size_t)c * PTOT + p0 + tx]);
    }
    __syncthreads();
#pragma unroll
    for (int k = 0; k < 4; ++k) {
        int p = p0 + ty + k * 8;
        dst[(size_t)p * 256 + c0 + tx] = tile[tx][ty + k * 8];
    }
}

// ---------- f32 -> bf16 elementwise (weights) ----------
__global__ void k_f2bf(const float* __restrict__ src, u16* __restrict__ dst, int n) {
    int i = blockIdx.x * 256 + threadIdx.x;
    if (i < n) dst[i] = f2bf(src[i]);
}

// ---------- GEMM: C[b,row,p] = sum_c A[row,c] * Bt[b,p,c] + bias[row] ----------
// A: (M,256) bf16 row-major; Bt: (2,PTOT,256) bf16; C: (2,M,PTOT) bf16 or f32.
template <bool OUT_F32>
__global__ __launch_bounds__(256) void k_gemm(const u16* __restrict__ A,
                                              const u16* __restrict__ Bt,
                                              void* __restrict__ Cout,
                                              const float* __restrict__ bias,
                                              int M) {
    __shared__ u16 As[128 * 32];
    __shared__ u16 Bs[128 * 32];
    const int tid = threadIdx.x;
    const int lane = tid & 63;
    const int wave = tid >> 6;
    const int wr = wave >> 1, wc = wave & 1;
    const int nb = blockIdx.x, mb = blockIdx.y, b = blockIdx.z;

    const u16* Ab = A + (size_t)(mb * 128) * 256;
    const u16* Bb = Bt + ((size_t)b * PTOT + (size_t)nb * 128) * 256;

    const int lrow = lane >> 2;        // 0..15 staging row within 16-row group
    const int lcol = (lane & 3) * 8;   // staging k offset (8 bf16 = 16B)
    const int lr = lane & 15;
    const int lk = lane >> 4;

    f32x4 acc[4][4];
#pragma unroll
    for (int m = 0; m < 4; ++m)
#pragma unroll
        for (int n = 0; n < 4; ++n) acc[m][n] = (f32x4)0.f;

    for (int k0 = 0; k0 < 256; k0 += 32) {
        __syncthreads();
        const int i0 = wave * 2;
#pragma unroll
        for (int ii = 0; ii < 2; ++ii) {
            const int i = i0 + ii;
            ASYNC_COPY16(Ab + (size_t)(i * 16 + lrow) * 256 + k0 + lcol,
                         As + i * 16 * 32);
            ASYNC_COPY16(Bb + (size_t)(i * 16 + lrow) * 256 + k0 + lcol,
                         Bs + i * 16 * 32);
        }
        __syncthreads();
        const bf16x8* Asv = (const bf16x8*)As;
        const bf16x8* Bsv = (const bf16x8*)Bs;
        bf16x8 afr[4], bfr[4];
#pragma unroll
        for (int m = 0; m < 4; ++m)
            afr[m] = Asv[(wr * 64 + m * 16 + lr) * 4 + lk];
#pragma unroll
        for (int n = 0; n < 4; ++n)
            bfr[n] = Bsv[(wc * 64 + n * 16 + lr) * 4 + lk];
#pragma unroll
        for (int m = 0; m < 4; ++m)
#pragma unroll
            for (int n = 0; n < 4; ++n)
                acc[m][n] = __builtin_amdgcn_mfma_f32_16x16x32_bf16(
                    afr[m], bfr[n], acc[m][n], 0, 0, 0);
    }

    // epilogue: C/D layout col=lane&15, row=(lane>>4)*4+reg  [m89-verified]
    const int cr = (lane >> 4) * 4;
    const int cc = lane & 15;
#pragma unroll
    for (int m = 0; m < 4; ++m) {
#pragma unroll
        for (int j = 0; j < 4; ++j) {
            const int row = mb * 128 + wr * 64 + m * 16 + cr + j;
            const float bv = bias[row];
            const size_t rbase =
                ((size_t)b * M + row) * PTOT + (size_t)nb * 128 + wc * 64 + cc;
#pragma unroll
            for (int n = 0; n < 4; ++n) {
                const float v = acc[m][n][j] + bv;
                if (OUT_F32)
                    ((float*)Cout)[rbase + n * 16] = v;
                else
                    ((u16*)Cout)[rbase + n * 16] = f2bf(v);
            }
        }
    }
}

// ---------- depthwise 3x3, zero padding ----------
__global__ __launch_bounds__(256) void k_dwconv(const u16* __restrict__ in,
                                                u16* __restrict__ out,
                                                const float* __restrict__ w,
                                                const float* __restrict__ bias,
                                                int C) {
    const int p = blockIdx.x * 256 + threadIdx.x;  // 0..PTOT-1
    const int ch = blockIdx.y;
    const int b = blockIdx.z;
    const int y = p / WIMG, x = p % WIMG;
    const size_t base = ((size_t)(b * C + ch)) * PTOT;
    float acc = bias[ch];
#pragma unroll
    for (int dy = -1; dy <= 1; ++dy) {
        const int yy = y + dy;
        if ((unsigned)yy >= (unsigned)WIMG) continue;
#pragma unroll
        for (int dx = -1; dx <= 1; ++dx) {
            const int xx = x + dx;
            if ((unsigned)xx >= (unsigned)WIMG) continue;
            acc += w[ch * 9 + (dy + 1) * 3 + (dx + 1)] *
                   bf2f(in[base + (size_t)yy * WIMG + xx]);
        }
    }
    out[base + p] = f2bf(acc);
}

// ---------- windowed channel cross-attention ----------
// q: (2,256,P) bf16; kv: (2,512,P) bf16 (k2 = ch 0..255, v2 = ch 256..511)
// out: (2,P,256) bf16 pixel-major
__global__ __launch_bounds__(256) void k_attn(const u16* __restrict__ q,
                                              const u16* __restrict__ kv,
                                              const float* __restrict__ temp,
                                              u16* __restrict__ outt) {
    __shared__ float qs[32][66], ks[32][66], vs[32][66];
    __shared__ float ss[32][33];
    __shared__ float invq[32], invk[32];
    const int tid = threadIdx.x;
    const int h = blockIdx.y, b = blockIdx.z;
    const int wy = blockIdx.x / 24, wx = blockIdx.x % 24;

    {   // cooperative load: thread t -> channel c=t/8, window-row y=t%8 (8 px)
        const int c = tid >> 3, y = tid & 7;
        const size_t px = (size_t)(wy * 8 + y) * WIMG + wx * 8;
        const u16* qp = q + ((size_t)b * 256 + h * 32 + c) * PTOT + px;
        const u16* kp = kv + ((size_t)b * 512 + h * 32 + c) * PTOT + px;
        const u16* vp = kv + ((size_t)b * 512 + 256 + h * 32 + c) * PTOT + px;
        bf16x8 qv = *(const bf16x8*)qp;
        bf16x8 kvv = *(const bf16x8*)kp;
        bf16x8 vv = *(const bf16x8*)vp;
#pragma unroll
        for (int i = 0; i < 8; ++i) {
            qs[c][y * 8 + i] = bf2f((u16)qv[i]);
            ks[c][y * 8 + i] = bf2f((u16)kvv[i]);
            vs[c][y * 8 + i] = bf2f((u16)vv[i]);
        }
    }
    __syncthreads();
    if (tid < 64) {  // row l2-norms of q and k2
        const int r = tid & 31;
        const float* rowp = (tid < 32) ? qs[r] : ks[r];
        float s = 0.f;
        for (int n = 0; n < 64; ++n) s += rowp[n] * rowp[n];
        const float inv = 1.f / fmaxf(sqrtf(s), 1e-12f);
        if (tid < 32) invq[r] = inv; else invk[r] = inv;
    }
    __syncthreads();
    const float tscale = temp[h];
    {   // scores: thread t -> row c=t/8, 4 cols d0..d0+3
        const int c = tid >> 3, d0 = (tid & 7) * 4;
        float dot[4] = {0.f, 0.f, 0.f, 0.f};
        for (int n = 0; n < 64; ++n) {
            const float qvn = qs[c][n];
#pragma unroll
            for (int i = 0; i < 4; ++i) dot[i] += qvn * ks[d0 + i][n];
        }
#pragma unroll
        for (int i = 0; i < 4; ++i)
            ss[c][d0 + i] = dot[i] * invq[c] * invk[d0 + i] * tscale;
    }
    __syncthreads();
    if (tid < 32) {  // softmax over d per row
        float m = -1e30f;
        for (int d = 0; d < 32; ++d) m = fmaxf(m, ss[tid][d]);
        float s = 0.f;
        for (int d = 0; d < 32; ++d) {
            const float e = __expf(ss[tid][d] - m);
            ss[tid][d] = e;
            s += e;
        }
        const float inv = 1.f / s;
        for (int d = 0; d < 32; ++d) ss[tid][d] *= inv;
    }
    __syncthreads();
    {   // out[c][n] = sum_d p[c][d]*v[d][n]; thread t -> pixel n=t%64, c-chunk
        const int n = tid & 63, c0 = (tid >> 6) * 8;
        float o[8] = {0.f, 0.f, 0.f, 0.f, 0.f, 0.f, 0.f, 0.f};
        for (int d = 0; d < 32; ++d) {
            const float vdn = vs[d][n];
#pragma unroll
            for (int j = 0; j < 8; ++j) o[j] += ss[c0 + j][d] * vdn;
        }
        bf16x8 ov;
#pragma unroll
        for (int j = 0; j < 8; ++j) ov[j] = (short)f2bf(o[j]);
        const size_t p = (size_t)(wy * 8 + (n >> 3)) * WIMG + wx * 8 + (n & 7);
        *(bf16x8*)(outt + ((size_t)b * PTOT + p) * 256 + h * 32 + c0) = ov;
    }
}

extern "C" void kernel_launch(void* const* d_in, const int* in_sizes, int n_in,
                              void* d_out, int out_size, void* d_ws, size_t ws_size,
                              hipStream_t stream) {
    (void)in_sizes; (void)n_in; (void)out_size; (void)ws_size;
    const float* x      = (const float*)d_in[0];
    const float* x2     = (const float*)d_in[1];
    const float* w_qkv  = (const float*)d_in[2];
    const float* b_qkv  = (const float*)d_in[3];
    const float* w_dw   = (const float*)d_in[4];
    const float* b_dw   = (const float*)d_in[5];
    const float* w_qkv2 = (const float*)d_in[6];
    const float* b_qkv2 = (const float*)d_in[7];
    const float* w_dw2  = (const float*)d_in[8];
    const float* b_dw2  = (const float*)d_in[9];
    const float* temp   = (const float*)d_in[10];
    const float* w_proj = (const float*)d_in[11];
    const float* b_proj = (const float*)d_in[12];
    float* out = (float*)d_out;

    char* ws = (char*)d_ws;
    const size_t SZ_T  = (size_t)2 * PTOT * 256 * 2;  // 37,748,736 B
    const size_t SZ_KV = (size_t)2 * PTOT * 512 * 2;  // 75,497,472 B
    u16* xt     = (u16*)(ws);
    u16* x2t    = (u16*)(ws + SZ_T);
    u16* qpre   = (u16*)(ws + 2 * SZ_T);
    u16* kvpre  = (u16*)(ws + 3 * SZ_T);
    u16* kvconv = (u16*)(ws + 3 * SZ_T + SZ_KV);
    u16* wq     = (u16*)(ws + 3 * SZ_T + 2 * SZ_KV);
    u16* wkv    = wq + 256 * 256;
    u16* wproj  = wkv + 512 * 256;
    u16* qconv  = xt;   // xt dead after q-GEMM
    u16* attnt  = x2t;  // x2t dead after kv-GEMM

    const dim3 tb(32, 8);
    k_transpose<<<dim3(PTOT / 32, 8, 2), tb, 0, stream>>>(x, xt);
    k_transpose<<<dim3(PTOT / 32, 8, 2), tb, 0, stream>>>(x2, x2t);
    k_f2bf<<<(256 * 256 + 255) / 256, 256, 0, stream>>>(w_qkv, wq, 256 * 256);
    k_f2bf<<<(512 * 256 + 255) / 256, 256, 0, stream>>>(w_qkv2 + 256 * 256, wkv, 512 * 256);
    k_f2bf<<<(256 * 256 + 255) / 256, 256, 0, stream>>>(w_proj, wproj, 256 * 256);

    // q = channels 0..255 of qkv(x); k2,v2 = channels 256..767 of qkv2(x2)
    k_gemm<false><<<dim3(PTOT / 128, 2, 2), 256, 0, stream>>>(wq, xt, qpre, b_qkv, 256);
    k_gemm<false><<<dim3(PTOT / 128, 4, 2), 256, 0, stream>>>(wkv, x2t, kvpre, b_qkv2 + 256, 512);

    k_dwconv<<<dim3(PTOT / 256, 256, 2), 256, 0, stream>>>(qpre, qconv, w_dw, b_dw, 256);
    k_dwconv<<<dim3(PTOT / 256, 512, 2), 256, 0, stream>>>(kvpre, kvconv, w_dw2 + 256 * 9, b_dw2 + 256, 512);

    k_attn<<<dim3(576, 8, 2), 256, 0, stream>>>(qconv, kvconv, temp, attnt);

    k_gemm<true><<<dim3(PTOT / 128, 2, 2), 256, 0, stream>>>(wproj, attnt, out, b_proj, 256);
}

// Round 2
// 346.745 us; speedup vs baseline: 1.7582x; 1.7582x over previous
//
#include <hip/hip_runtime.h>
#include <stdint.h>

typedef unsigned short u16;
typedef __attribute__((ext_vector_type(8))) short bf16x8;
typedef __attribute__((ext_vector_type(4))) float f32x4;

#define PTOT 36864
#define WIMG 192

__device__ __forceinline__ float bf2f(u16 h) {
    union { uint32_t u; float f; } v; v.u = ((uint32_t)h) << 16; return v.f;
}
__device__ __forceinline__ u16 f2bf(float f) {
    union { float f; uint32_t u; } v; v.f = f;
    uint32_t u = v.u;
    return (u16)((u + 0x7FFFu + ((u >> 16) & 1u)) >> 16);
}

#define ASYNC_COPY16(gp, lp)                                                     \
    __builtin_amdgcn_global_load_lds(                                            \
        (const __attribute__((address_space(1))) void*)(gp),                     \
        (__attribute__((address_space(3))) void*)(lp), 16, 0, 0)

// ---------- transpose+convert: x (b,256,P) f32 -> xt (b,P,256) bf16 ----------
__global__ __launch_bounds__(256) void k_transpose(const float* __restrict__ x,
                                                   u16* __restrict__ xt) {
    __shared__ u16 tile[32][33];
    const int tx = threadIdx.x, ty = threadIdx.y;  // (32, 8)
    const int p0 = blockIdx.x * 32, c0 = blockIdx.y * 32, b = blockIdx.z;
    const float* src = x + (size_t)b * 256 * PTOT;
    u16* dst = xt + (size_t)b * PTOT * 256;
#pragma unroll
    for (int k = 0; k < 4; ++k) {
        int c = c0 + ty + k * 8;
        tile[ty + k * 8][tx] = f2bf(src[(size_t)c * PTOT + p0 + tx]);
    }
    __syncthreads();
#pragma unroll
    for (int k = 0; k < 4; ++k) {
        int p = p0 + ty + k * 8;
        dst[(size_t)p * 256 + c0 + tx] = tile[tx][ty + k * 8];
    }
}

// ---------- f32 -> bf16 elementwise (weights) ----------
__global__ void k_f2bf(const float* __restrict__ src, u16* __restrict__ dst, int n) {
    int i = blockIdx.x * 256 + threadIdx.x;
    if (i < n) dst[i] = f2bf(src[i]);
}

// ---------- GEMM: C[b,row,p] = sum_c A[row,c] * Bt[b,p,c] + bias[row] ----------
// A: (M,256) bf16 row-major; Bt: (2,PTOT,256) bf16; C: (2,M,PTOT) bf16 or f32.
template <bool OUT_F32>
__global__ __launch_bounds__(256) void k_gemm(const u16* __restrict__ A,
                                              const u16* __restrict__ Bt,
                                              void* __restrict__ Cout,
                                              const float* __restrict__ bias,
                                              int M) {
    __shared__ u16 As[128 * 32];
    __shared__ u16 Bs[128 * 32];
    const int tid = threadIdx.x;
    const int lane = tid & 63;
    const int wave = tid >> 6;
    const int wr = wave >> 1, wc = wave & 1;
    const int nb = blockIdx.x, mb = blockIdx.y, b = blockIdx.z;

    const u16* Ab = A + (size_t)(mb * 128) * 256;
    const u16* Bb = Bt + ((size_t)b * PTOT + (size_t)nb * 128) * 256;

    const int lrow = lane >> 2;        // 0..15 staging row within 16-row group
    const int lcol = (lane & 3) * 8;   // staging k offset (8 bf16 = 16B)
    const int lr = lane & 15;
    const int lk = lane >> 4;

    f32x4 acc[4][4];
#pragma unroll
    for (int m = 0; m < 4; ++m)
#pragma unroll
        for (int n = 0; n < 4; ++n) acc[m][n] = (f32x4)0.f;

    for (int k0 = 0; k0 < 256; k0 += 32) {
        __syncthreads();
        const int i0 = wave * 2;
#pragma unroll
        for (int ii = 0; ii < 2; ++ii) {
            const int i = i0 + ii;
            ASYNC_COPY16(Ab + (size_t)(i * 16 + lrow) * 256 + k0 + lcol,
                         As + i * 16 * 32);
            ASYNC_COPY16(Bb + (size_t)(i * 16 + lrow) * 256 + k0 + lcol,
                         Bs + i * 16 * 32);
        }
        __syncthreads();
        const bf16x8* Asv = (const bf16x8*)As;
        const bf16x8* Bsv = (const bf16x8*)Bs;
        bf16x8 afr[4], bfr[4];
#pragma unroll
        for (int m = 0; m < 4; ++m)
            afr[m] = Asv[(wr * 64 + m * 16 + lr) * 4 + lk];
#pragma unroll
        for (int n = 0; n < 4; ++n)
            bfr[n] = Bsv[(wc * 64 + n * 16 + lr) * 4 + lk];
#pragma unroll
        for (int m = 0; m < 4; ++m)
#pragma unroll
            for (int n = 0; n < 4; ++n)
                acc[m][n] = __builtin_amdgcn_mfma_f32_16x16x32_bf16(
                    afr[m], bfr[n], acc[m][n], 0, 0, 0);
    }

    // epilogue: C/D layout col=lane&15, row=(lane>>4)*4+reg  [m89-verified]
    const int cr = (lane >> 4) * 4;
    const int cc = lane & 15;
#pragma unroll
    for (int m = 0; m < 4; ++m) {
#pragma unroll
        for (int j = 0; j < 4; ++j) {
            const int row = mb * 128 + wr * 64 + m * 16 + cr + j;
            const float bv = bias[row];
            const size_t rbase =
                ((size_t)b * M + row) * PTOT + (size_t)nb * 128 + wc * 64 + cc;
#pragma unroll
            for (int n = 0; n < 4; ++n) {
                const float v = acc[m][n][j] + bv;
                if (OUT_F32)
                    ((float*)Cout)[rbase + n * 16] = v;
                else
                    ((u16*)Cout)[rbase + n * 16] = f2bf(v);
            }
        }
    }
}

// ---------- depthwise 3x3, zero padding, 8 px/thread vectorized ----------
__global__ __launch_bounds__(256) void k_dwconv(const u16* __restrict__ in,
                                                u16* __restrict__ out,
                                                const float* __restrict__ w,
                                                const float* __restrict__ bias,
                                                int C) {
    const int vec = blockIdx.x * 256 + threadIdx.x;  // 0..4607 per image
    const int ch = blockIdx.y, b = blockIdx.z;
    const int y = vec / 24, xv = vec - y * 24;       // row, 8-px column block
    const size_t base = ((size_t)(b * C + ch)) * PTOT;
    const float* wc9 = w + ch * 9;

    float acc[8];
    const float bv = bias[ch];
#pragma unroll
    for (int i = 0; i < 8; ++i) acc[i] = bv;

#pragma unroll
    for (int dy = -1; dy <= 1; ++dy) {
        const int yy = y + dy;
        if ((unsigned)yy >= (unsigned)WIMG) continue;
        const u16* row = in + base + (size_t)yy * WIMG + xv * 8;
        const bf16x8 cv = *(const bf16x8*)row;
        float p[10];
        p[0] = (xv > 0) ? bf2f(row[-1]) : 0.f;
        p[9] = (xv < 23) ? bf2f(row[8]) : 0.f;
#pragma unroll
        for (int i = 0; i < 8; ++i) p[i + 1] = bf2f((u16)cv[i]);
        const float wa = wc9[(dy + 1) * 3 + 0];
        const float wb = wc9[(dy + 1) * 3 + 1];
        const float wcv = wc9[(dy + 1) * 3 + 2];
#pragma unroll
        for (int i = 0; i < 8; ++i)
            acc[i] += wa * p[i] + wb * p[i + 1] + wcv * p[i + 2];
    }

    bf16x8 ov;
#pragma unroll
    for (int i = 0; i < 8; ++i) ov[i] = (short)f2bf(acc[i]);
    *(bf16x8*)(out + base + (size_t)y * WIMG + xv * 8) = ov;
}

// ---------- windowed channel cross-attention ----------
// q: (2,256,P) bf16; kv: (2,512,P) bf16 (k2 = ch 0..255, v2 = ch 256..511)
// out: (2,P,256) bf16 pixel-major
__global__ __launch_bounds__(256) void k_attn(const u16* __restrict__ q,
                                              const u16* __restrict__ kv,
                                              const float* __restrict__ temp,
                                              u16* __restrict__ outt) {
    __shared__ float qs[32][66], ks[32][66], vs[32][66];
    __shared__ float ss[32][33];
    __shared__ float invq[32], invk[32];
    const int tid = threadIdx.x;
    const int h = blockIdx.y, b = blockIdx.z;
    const int wy = blockIdx.x / 24, wx = blockIdx.x % 24;

    {   // cooperative load: thread t -> channel c=t/8, window-row y=t%8 (8 px)
        const int c = tid >> 3, y = tid & 7;
        const size_t px = (size_t)(wy * 8 + y) * WIMG + wx * 8;
        const u16* qp = q + ((size_t)b * 256 + h * 32 + c) * PTOT + px;
        const u16* kp = kv + ((size_t)b * 512 + h * 32 + c) * PTOT + px;
        const u16* vp = kv + ((size_t)b * 512 + 256 + h * 32 + c) * PTOT + px;
        bf16x8 qv = *(const bf16x8*)qp;
        bf16x8 kvv = *(const bf16x8*)kp;
        bf16x8 vv = *(const bf16x8*)vp;
#pragma unroll
        for (int i = 0; i < 8; ++i) {
            qs[c][y * 8 + i] = bf2f((u16)qv[i]);
            ks[c][y * 8 + i] = bf2f((u16)kvv[i]);
            vs[c][y * 8 + i] = bf2f((u16)vv[i]);
        }
    }
    __syncthreads();
    if (tid < 64) {  // row l2-norms of q and k2
        const int r = tid & 31;
        const float* rowp = (tid < 32) ? qs[r] : ks[r];
        float s = 0.f;
        for (int n = 0; n < 64; ++n) s += rowp[n] * rowp[n];
        const float inv = 1.f / fmaxf(sqrtf(s), 1e-12f);
        if (tid < 32) invq[r] = inv; else invk[r] = inv;
    }
    __syncthreads();
    const float tscale = temp[h];
    {   // scores: thread t -> row c=t/8, 4 cols d0..d0+3
        const int c = tid >> 3, d0 = (tid & 7) * 4;
        float dot[4] = {0.f, 0.f, 0.f, 0.f};
        for (int n = 0; n < 64; ++n) {
            const float qvn = qs[c][n];
#pragma unroll
            for (int i = 0; i < 4; ++i) dot[i] += qvn * ks[d0 + i][n];
        }
#pragma unroll
        for (int i = 0; i < 4; ++i)
            ss[c][d0 + i] = dot[i] * invq[c] * invk[d0 + i] * tscale;
    }
    __syncthreads();
    if (tid < 32) {  // softmax over d per row
        float m = -1e30f;
        for (int d = 0; d < 32; ++d) m = fmaxf(m, ss[tid][d]);
        float s = 0.f;
        for (int d = 0; d < 32; ++d) {
            const float e = __expf(ss[tid][d] - m);
            ss[tid][d] = e;
            s += e;
        }
        const float inv = 1.f / s;
        for (int d = 0; d < 32; ++d) ss[tid][d] *= inv;
    }
    __syncthreads();
    {   // out[c][n] = sum_d p[c][d]*v[d][n]; thread t -> pixel n=t%64, c-chunk
        const int n = tid & 63, c0 = (tid >> 6) * 8;
        float o[8] = {0.f, 0.f, 0.f, 0.f, 0.f, 0.f, 0.f, 0.f};
        for (int d = 0; d < 32; ++d) {
            const float vdn = vs[d][n];
#pragma unroll
            for (int j = 0; j < 8; ++j) o[j] += ss[c0 + j][d] * vdn;
        }
        bf16x8 ov;
#pragma unroll
        for (int j = 0; j < 8; ++j) ov[j] = (short)f2bf(o[j]);
        const size_t p = (size_t)(wy * 8 + (n >> 3)) * WIMG + wx * 8 + (n & 7);
        *(bf16x8*)(outt + ((size_t)b * PTOT + p) * 256 + h * 32 + c0) = ov;
    }
}

extern "C" void kernel_launch(void* const* d_in, const int* in_sizes, int n_in,
                              void* d_out, int out_size, void* d_ws, size_t ws_size,
                              hipStream_t stream) {
    (void)in_sizes; (void)n_in; (void)out_size; (void)ws_size;
    const float* x      = (const float*)d_in[0];
    const float* x2     = (const float*)d_in[1];
    const float* w_qkv  = (const float*)d_in[2];
    const float* b_qkv  = (const float*)d_in[3];
    const float* w_dw   = (const float*)d_in[4];
    const float* b_dw   = (const float*)d_in[5];
    const float* w_qkv2 = (const float*)d_in[6];
    const float* b_qkv2 = (const float*)d_in[7];
    const float* w_dw2  = (const float*)d_in[8];
    const float* b_dw2  = (const float*)d_in[9];
    const float* temp   = (const float*)d_in[10];
    const float* w_proj = (const float*)d_in[11];
    const float* b_proj = (const float*)d_in[12];
    float* out = (float*)d_out;

    char* ws = (char*)d_ws;
    const size_t SZ_T  = (size_t)2 * PTOT * 256 * 2;  // 37,748,736 B
    const size_t SZ_KV = (size_t)2 * PTOT * 512 * 2;  // 75,497,472 B
    u16* xt     = (u16*)(ws);
    u16* x2t    = (u16*)(ws + SZ_T);
    u16* qpre   = (u16*)(ws + 2 * SZ_T);
    u16* kvpre  = (u16*)(ws + 3 * SZ_T);
    u16* kvconv = (u16*)(ws + 3 * SZ_T + SZ_KV);
    u16* wq     = (u16*)(ws + 3 * SZ_T + 2 * SZ_KV);
    u16* wkv    = wq + 256 * 256;
    u16* wproj  = wkv + 512 * 256;
    u16* qconv  = xt;   // xt dead after q-GEMM
    u16* attnt  = x2t;  // x2t dead after kv-GEMM

    const dim3 tb(32, 8);
    k_transpose<<<dim3(PTOT / 32, 8, 2), tb, 0, stream>>>(x, xt);
    k_transpose<<<dim3(PTOT / 32, 8, 2), tb, 0, stream>>>(x2, x2t);
    k_f2bf<<<(256 * 256 + 255) / 256, 256, 0, stream>>>(w_qkv, wq, 256 * 256);
    k_f2bf<<<(512 * 256 + 255) / 256, 256, 0, stream>>>(w_qkv2 + 256 * 256, wkv, 512 * 256);
    k_f2bf<<<(256 * 256 + 255) / 256, 256, 0, stream>>>(w_proj, wproj, 256 * 256);

    // q = channels 0..255 of qkv(x); k2,v2 = channels 256..767 of qkv2(x2)
    k_gemm<false><<<dim3(PTOT / 128, 2, 2), 256, 0, stream>>>(wq, xt, qpre, b_qkv, 256);
    k_gemm<false><<<dim3(PTOT / 128, 4, 2), 256, 0, stream>>>(wkv, x2t, kvpre, b_qkv2 + 256, 512);

    k_dwconv<<<dim3(4608 / 256, 256, 2), 256, 0, stream>>>(qpre, qconv, w_dw, b_dw, 256);
    k_dwconv<<<dim3(4608 / 256, 512, 2), 256, 0, stream>>>(kvpre, kvconv, w_dw2 + 256 * 9, b_dw2 + 256, 512);

    k_attn<<<dim3(576, 8, 2), 256, 0, stream>>>(qconv, kvconv, temp, attnt);

    k_gemm<true><<<dim3(PTOT / 128, 2, 2), 256, 0, stream>>>(wproj, attnt, out, b_proj, 256);
}

// Round 3
// 253.014 us; speedup vs baseline: 2.4095x; 1.3705x over previous
//
#include <hip/hip_runtime.h>
#include <stdint.h>

typedef unsigned short u16;
typedef __attribute__((ext_vector_type(4))) unsigned short u16x4;
typedef __attribute__((ext_vector_type(8))) short bf16x8;
typedef __attribute__((ext_vector_type(4))) float f32x4;

#define PTOT 36864
#define WIMG 192

__device__ __forceinline__ float bf2f(u16 h) {
    union { uint32_t u; float f; } v; v.u = ((uint32_t)h) << 16; return v.f;
}
__device__ __forceinline__ u16 f2bf(float f) {
    union { float f; uint32_t u; } v; v.f = f;
    uint32_t u = v.u;
    return (u16)((u + 0x7FFFu + ((u >> 16) & 1u)) >> 16);
}

#define ASYNC_COPY16(gp, lp)                                                     \
    __builtin_amdgcn_global_load_lds(                                            \
        (const __attribute__((address_space(1))) void*)(gp),                     \
        (__attribute__((address_space(3))) void*)(lp), 16, 0, 0)

// ---------- transpose+convert: x (b,256,P) f32 -> xt (b,P,256) bf16 ----------
__global__ __launch_bounds__(256) void k_transpose(const float* __restrict__ x,
                                                   u16* __restrict__ xt) {
    __shared__ u16 tile[32][33];
    const int tx = threadIdx.x, ty = threadIdx.y;  // (32, 8)
    const int p0 = blockIdx.x * 32, c0 = blockIdx.y * 32, b = blockIdx.z;
    const float* src = x + (size_t)b * 256 * PTOT;
    u16* dst = xt + (size_t)b * PTOT * 256;
#pragma unroll
    for (int k = 0; k < 4; ++k) {
        int c = c0 + ty + k * 8;
        tile[ty + k * 8][tx] = f2bf(src[(size_t)c * PTOT + p0 + tx]);
    }
    __syncthreads();
#pragma unroll
    for (int k = 0; k < 4; ++k) {
        int p = p0 + ty + k * 8;
        dst[(size_t)p * 256 + c0 + tx] = tile[tx][ty + k * 8];
    }
}

// ---------- f32 -> bf16 elementwise (weights) ----------
__global__ void k_f2bf(const float* __restrict__ src, u16* __restrict__ dst, int n) {
    int i = blockIdx.x * 256 + threadIdx.x;
    if (i < n) dst[i] = f2bf(src[i]);
}

// ---------- GEMM: C[b,row,p] = sum_c A[row,c] * Bt[b,p,c] + bias[row] ----------
template <bool OUT_F32>
__global__ __launch_bounds__(256) void k_gemm(const u16* __restrict__ A,
                                              const u16* __restrict__ Bt,
                                              void* __restrict__ Cout,
                                              const float* __restrict__ bias,
                                              int M) {
    __shared__ u16 As[128 * 32];
    __shared__ u16 Bs[128 * 32];
    const int tid = threadIdx.x;
    const int lane = tid & 63;
    const int wave = tid >> 6;
    const int wr = wave >> 1, wc = wave & 1;
    const int nb = blockIdx.x, mb = blockIdx.y, b = blockIdx.z;

    const u16* Ab = A + (size_t)(mb * 128) * 256;
    const u16* Bb = Bt + ((size_t)b * PTOT + (size_t)nb * 128) * 256;

    const int lrow = lane >> 2;
    const int lcol = (lane & 3) * 8;
    const int lr = lane & 15;
    const int lk = lane >> 4;

    f32x4 acc[4][4];
#pragma unroll
    for (int m = 0; m < 4; ++m)
#pragma unroll
        for (int n = 0; n < 4; ++n) acc[m][n] = (f32x4)0.f;

    for (int k0 = 0; k0 < 256; k0 += 32) {
        __syncthreads();
        const int i0 = wave * 2;
#pragma unroll
        for (int ii = 0; ii < 2; ++ii) {
            const int i = i0 + ii;
            ASYNC_COPY16(Ab + (size_t)(i * 16 + lrow) * 256 + k0 + lcol,
                         As + i * 16 * 32);
            ASYNC_COPY16(Bb + (size_t)(i * 16 + lrow) * 256 + k0 + lcol,
                         Bs + i * 16 * 32);
        }
        __syncthreads();
        const bf16x8* Asv = (const bf16x8*)As;
        const bf16x8* Bsv = (const bf16x8*)Bs;
        bf16x8 afr[4], bfr[4];
#pragma unroll
        for (int m = 0; m < 4; ++m)
            afr[m] = Asv[(wr * 64 + m * 16 + lr) * 4 + lk];
#pragma unroll
        for (int n = 0; n < 4; ++n)
            bfr[n] = Bsv[(wc * 64 + n * 16 + lr) * 4 + lk];
#pragma unroll
        for (int m = 0; m < 4; ++m)
#pragma unroll
            for (int n = 0; n < 4; ++n)
                acc[m][n] = __builtin_amdgcn_mfma_f32_16x16x32_bf16(
                    afr[m], bfr[n], acc[m][n], 0, 0, 0);
    }

    const int cr = (lane >> 4) * 4;
    const int cc = lane & 15;
#pragma unroll
    for (int m = 0; m < 4; ++m) {
#pragma unroll
        for (int j = 0; j < 4; ++j) {
            const int row = mb * 128 + wr * 64 + m * 16 + cr + j;
            const float bv = bias[row];
            const size_t rbase =
                ((size_t)b * M + row) * PTOT + (size_t)nb * 128 + wc * 64 + cc;
#pragma unroll
            for (int n = 0; n < 4; ++n) {
                const float v = acc[m][n][j] + bv;
                if (OUT_F32)
                    ((float*)Cout)[rbase + n * 16] = v;
                else
                    ((u16*)Cout)[rbase + n * 16] = f2bf(v);
            }
        }
    }
}

// ---------- depthwise 3x3, zero padding, 8 px/thread vectorized ----------
__global__ __launch_bounds__(256) void k_dwconv(const u16* __restrict__ in,
                                                u16* __restrict__ out,
                                                const float* __restrict__ w,
                                                const float* __restrict__ bias,
                                                int C) {
    const int vec = blockIdx.x * 256 + threadIdx.x;
    const int ch = blockIdx.y, b = blockIdx.z;
    const int y = vec / 24, xv = vec - y * 24;
    const size_t base = ((size_t)(b * C + ch)) * PTOT;
    const float* wc9 = w + ch * 9;

    float acc[8];
    const float bv = bias[ch];
#pragma unroll
    for (int i = 0; i < 8; ++i) acc[i] = bv;

#pragma unroll
    for (int dy = -1; dy <= 1; ++dy) {
        const int yy = y + dy;
        if ((unsigned)yy >= (unsigned)WIMG) continue;
        const u16* row = in + base + (size_t)yy * WIMG + xv * 8;
        const bf16x8 cv = *(const bf16x8*)row;
        float p[10];
        p[0] = (xv > 0) ? bf2f(row[-1]) : 0.f;
        p[9] = (xv < 23) ? bf2f(row[8]) : 0.f;
#pragma unroll
        for (int i = 0; i < 8; ++i) p[i + 1] = bf2f((u16)cv[i]);
        const float wa = wc9[(dy + 1) * 3 + 0];
        const float wb = wc9[(dy + 1) * 3 + 1];
        const float wcv = wc9[(dy + 1) * 3 + 2];
#pragma unroll
        for (int i = 0; i < 8; ++i)
            acc[i] += wa * p[i] + wb * p[i + 1] + wcv * p[i + 2];
    }

    bf16x8 ov;
#pragma unroll
    for (int i = 0; i < 8; ++i) ov[i] = (short)f2bf(acc[i]);
    *(bf16x8*)(out + base + (size_t)y * WIMG + xv * 8) = ov;
}

// ---------- windowed channel cross-attention, 4 windows/block, MFMA ----------
// q: (2,256,P) bf16; kv: (2,512,P) bf16 (k2 ch 0..255, v2 ch 256..511)
// out: (2,P,256) bf16 pixel-major.  grid (144=24x6, 8, 2), 256 threads.
__global__ __launch_bounds__(256) void k_attn(const u16* __restrict__ q,
                                              const u16* __restrict__ kv,
                                              const float* __restrict__ temp,
                                              u16* __restrict__ outt) {
    // LDS map (u16 units): Q[0..9248) K[9248..18496) VT[18496..28768)
    // IQ f32 @28768, IK f32 @29024.  SS(f32) overlays K; P overlays Q.
    __shared__ __align__(16) u16 lds[29280];
    u16* Q = lds;                 // [w:2312][c:72-stride][64+8pad]
    u16* K = lds + 9248;
    u16* VT = lds + 18496;        // [w:2568][n:40-stride][32+8pad]
    float* IQ = (float*)(lds + 28768);
    float* IK = (float*)(lds + 29024);
    float* SS = (float*)(lds + 9248);  // [w:1156][c:36-stride][32]
    u16* P = lds;                      // [w:2312][c:40-stride][32]

    const int tid = threadIdx.x;
    const int lane = tid & 63;
    const int wv = tid >> 6;  // wave id == window id for MFMA phases
    const int h = blockIdx.y, b = blockIdx.z;
    const int wy = blockIdx.x / 6, wxg = blockIdx.x % 6;
    const int px0 = wxg * 32;

    const size_t qbase = ((size_t)b * 256 + h * 32) * PTOT;
    const size_t kbase = ((size_t)b * 512 + h * 32) * PTOT;
    const size_t vbase = kbase + (size_t)256 * PTOT;

    // ---- stage q,k row-major + v transposed ----
#pragma unroll
    for (int it = 0; it < 4; ++it) {
        const int L = it * 256 + tid;
        const int c = L >> 5, rem = L & 31, rr = rem >> 2, w = rem & 3;
        const size_t gp = (size_t)(wy * 8 + rr) * WIMG + px0 + w * 8;
        bf16x8 qv = *(const bf16x8*)(q + qbase + (size_t)c * PTOT + gp);
        bf16x8 kvv = *(const bf16x8*)(kv + kbase + (size_t)c * PTOT + gp);
        bf16x8 vv = *(const bf16x8*)(kv + vbase + (size_t)c * PTOT + gp);
        *(bf16x8*)(Q + w * 2312 + c * 72 + rr * 8) = qv;
        *(bf16x8*)(K + w * 2312 + c * 72 + rr * 8) = kvv;
        u16* vt = VT + w * 2568 + rr * 8 * 40 + c;
#pragma unroll
        for (int j = 0; j < 8; ++j) vt[j * 40] = (u16)vv[j];
    }
    __syncthreads();

    // ---- row l2-norms: t<128 -> q rows, t>=128 -> k rows ----
    {
        const int w = (tid >> 5) & 3, c = tid & 31;
        const u16* row = (tid < 128 ? Q : K) + w * 2312 + c * 72;
        float s = 0.f;
#pragma unroll
        for (int j = 0; j < 8; ++j) {
            bf16x8 v = *(const bf16x8*)(row + j * 8);
#pragma unroll
            for (int i = 0; i < 8; ++i) { float f = bf2f((u16)v[i]); s += f * f; }
        }
        const float inv = 1.f / fmaxf(sqrtf(s), 1e-12f);
        (tid < 128 ? IQ : IK)[w * 32 + c] = inv;
    }
    __syncthreads();

    // ---- scores: wave wv computes 32x32 raw dots for window wv ----
    {
        const int lr = lane & 15, lk = lane >> 4;
        f32x4 s00 = (f32x4)0.f, s01 = (f32x4)0.f, s10 = (f32x4)0.f, s11 = (f32x4)0.f;
        const u16* Qw = Q + wv * 2312 + lk * 8;
        const u16* Kw = K + wv * 2312 + lk * 8;
#pragma unroll
        for (int kb = 0; kb < 2; ++kb) {
            bf16x8 a0 = *(const bf16x8*)(Qw + lr * 72 + kb * 32);
            bf16x8 a1 = *(const bf16x8*)(Qw + (16 + lr) * 72 + kb * 32);
            bf16x8 b0 = *(const bf16x8*)(Kw + lr * 72 + kb * 32);
            bf16x8 b1 = *(const bf16x8*)(Kw + (16 + lr) * 72 + kb * 32);
            s00 = __builtin_amdgcn_mfma_f32_16x16x32_bf16(a0, b0, s00, 0, 0, 0);
            s01 = __builtin_amdgcn_mfma_f32_16x16x32_bf16(a0, b1, s01, 0, 0, 0);
            s10 = __builtin_amdgcn_mfma_f32_16x16x32_bf16(a1, b0, s10, 0, 0, 0);
            s11 = __builtin_amdgcn_mfma_f32_16x16x32_bf16(a1, b1, s11, 0, 0, 0);
        }
        float* srow = SS + wv * 1156;
        const int cr = lk * 4, cc = lr;
#pragma unroll
        for (int j = 0; j < 4; ++j) {
            srow[(cr + j) * 36 + cc] = s00[j];
            srow[(cr + j) * 36 + 16 + cc] = s01[j];
            srow[(16 + cr + j) * 36 + cc] = s10[j];
            srow[(16 + cr + j) * 36 + 16 + cc] = s11[j];
        }
    }
    __syncthreads();

    // ---- softmax: thread (w,c) owns one score row, fully in-register ----
    if (tid < 128) {
        const int w = tid >> 5, c = tid & 31;
        const float* srow = SS + w * 1156 + c * 36;
        const float* ik = IK + w * 32;
        const float iq = IQ[w * 32 + c] * temp[h];
        float sv[32];
        float mx = -1e30f;
#pragma unroll
        for (int d = 0; d < 32; ++d) {
            sv[d] = srow[d] * ik[d] * iq;
            mx = fmaxf(mx, sv[d]);
        }
        float sum = 0.f;
#pragma unroll
        for (int d = 0; d < 32; ++d) {
            sv[d] = __expf(sv[d] - mx);
            sum += sv[d];
        }
        const float inv = 1.f / sum;
        u16* prow = P + w * 2312 + c * 40;
#pragma unroll
        for (int ch = 0; ch < 4; ++ch) {
            bf16x8 pv;
#pragma unroll
            for (int i = 0; i < 8; ++i) pv[i] = (short)f2bf(sv[ch * 8 + i] * inv);
            *(bf16x8*)(prow + ch * 8) = pv;
        }
    }
    __syncthreads();

    // ---- PV: wave wv computes out 32x64 for window wv; K=32 one MFMA/tile ----
    {
        const int lr = lane & 15, lk = lane >> 4;
        bf16x8 pa0 = *(const bf16x8*)(P + wv * 2312 + lr * 40 + lk * 8);
        bf16x8 pa1 = *(const bf16x8*)(P + wv * 2312 + (16 + lr) * 40 + lk * 8);
        f32x4 o0[4], o1[4];
#pragma unroll
        for (int ni = 0; ni < 4; ++ni) { o0[ni] = (f32x4)0.f; o1[ni] = (f32x4)0.f; }
#pragma unroll
        for (int ni = 0; ni < 4; ++ni) {
            bf16x8 vb = *(const bf16x8*)(VT + wv * 2568 + (ni * 16 + lr) * 40 + lk * 8);
            o0[ni] = __builtin_amdgcn_mfma_f32_16x16x32_bf16(pa0, vb, o0[ni], 0, 0, 0);
            o1[ni] = __builtin_amdgcn_mfma_f32_16x16x32_bf16(pa1, vb, o1[ni], 0, 0, 0);
        }
#pragma unroll
        for (int ni = 0; ni < 4; ++ni) {
            const int n = ni * 16 + lr;
            const size_t gp = (size_t)(wy * 8 + (n >> 3)) * WIMG + px0 + wv * 8 + (n & 7);
            u16* op = outt + ((size_t)b * PTOT + gp) * 256 + h * 32;
            u16x4 pk0, pk1;
#pragma unroll
            for (int j = 0; j < 4; ++j) { pk0[j] = f2bf(o0[ni][j]); pk1[j] = f2bf(o1[ni][j]); }
            *(u16x4*)(op + lk * 4) = pk0;
            *(u16x4*)(op + 16 + lk * 4) = pk1;
        }
    }
}

extern "C" void kernel_launch(void* const* d_in, const int* in_sizes, int n_in,
                              void* d_out, int out_size, void* d_ws, size_t ws_size,
                              hipStream_t stream) {
    (void)in_sizes; (void)n_in; (void)out_size; (void)ws_size;
    const float* x      = (const float*)d_in[0];
    const float* x2     = (const float*)d_in[1];
    const float* w_qkv  = (const float*)d_in[2];
    const float* b_qkv  = (const float*)d_in[3];
    const float* w_dw   = (const float*)d_in[4];
    const float* b_dw   = (const float*)d_in[5];
    const float* w_qkv2 = (const float*)d_in[6];
    const float* b_qkv2 = (const float*)d_in[7];
    const float* w_dw2  = (const float*)d_in[8];
    const float* b_dw2  = (const float*)d_in[9];
    const float* temp   = (const float*)d_in[10];
    const float* w_proj = (const float*)d_in[11];
    const float* b_proj = (const float*)d_in[12];
    float* out = (float*)d_out;

    char* ws = (char*)d_ws;
    const size_t SZ_T  = (size_t)2 * PTOT * 256 * 2;
    const size_t SZ_KV = (size_t)2 * PTOT * 512 * 2;
    u16* xt     = (u16*)(ws);
    u16* x2t    = (u16*)(ws + SZ_T);
    u16* qpre   = (u16*)(ws + 2 * SZ_T);
    u16* kvpre  = (u16*)(ws + 3 * SZ_T);
    u16* kvconv = (u16*)(ws + 3 * SZ_T + SZ_KV);
    u16* wq     = (u16*)(ws + 3 * SZ_T + 2 * SZ_KV);
    u16* wkv    = wq + 256 * 256;
    u16* wproj  = wkv + 512 * 256;
    u16* qconv  = xt;   // xt dead after q-GEMM
    u16* attnt  = x2t;  // x2t dead after kv-GEMM

    const dim3 tb(32, 8);
    k_transpose<<<dim3(PTOT / 32, 8, 2), tb, 0, stream>>>(x, xt);
    k_transpose<<<dim3(PTOT / 32, 8, 2), tb, 0, stream>>>(x2, x2t);
    k_f2bf<<<(256 * 256 + 255) / 256, 256, 0, stream>>>(w_qkv, wq, 256 * 256);
    k_f2bf<<<(512 * 256 + 255) / 256, 256, 0, stream>>>(w_qkv2 + 256 * 256, wkv, 512 * 256);
    k_f2bf<<<(256 * 256 + 255) / 256, 256, 0, stream>>>(w_proj, wproj, 256 * 256);

    k_gemm<false><<<dim3(PTOT / 128, 2, 2), 256, 0, stream>>>(wq, xt, qpre, b_qkv, 256);
    k_gemm<false><<<dim3(PTOT / 128, 4, 2), 256, 0, stream>>>(wkv, x2t, kvpre, b_qkv2 + 256, 512);

    k_dwconv<<<dim3(4608 / 256, 256, 2), 256, 0, stream>>>(qpre, qconv, w_dw, b_dw, 256);
    k_dwconv<<<dim3(4608 / 256, 512, 2), 256, 0, stream>>>(kvpre, kvconv, w_dw2 + 256 * 9, b_dw2 + 256, 512);

    k_attn<<<dim3(144, 8, 2), 256, 0, stream>>>(qconv, kvconv, temp, attnt);

    k_gemm<true><<<dim3(PTOT / 128, 2, 2), 256, 0, stream>>>(wproj, attnt, out, b_proj, 256);
}